// Round 8
// baseline (478.681 us; speedup 1.0000x reference)
//
#include <hip/hip_runtime.h>

typedef __attribute__((ext_vector_type(8))) short s16x8;
typedef __attribute__((ext_vector_type(4))) float f32x4;

#define DEV static __device__ __forceinline__

DEV float b2f(unsigned short u){
  unsigned int i = ((unsigned int)u) << 16;
  float f; __builtin_memcpy(&f, &i, 4); return f;
}
DEV unsigned short f2b(float f){
  unsigned int i; __builtin_memcpy(&i, &f, 4);
  i = i + 0x7fffu + ((i >> 16) & 1u);
  return (unsigned short)(i >> 16);
}
DEV f32x4 mfma16(s16x8 a, s16x8 b, f32x4 c){
  return __builtin_amdgcn_mfma_f32_16x16x32_bf16(a, b, c, 0, 0, 0);
}
DEV s16x8 ld8f(const float* p){
  const float4* q4 = (const float4*)p;
  float4 a = q4[0], b = q4[1];
  s16x8 r;
  r[0]=(short)f2b(a.x); r[1]=(short)f2b(a.y); r[2]=(short)f2b(a.z); r[3]=(short)f2b(a.w);
  r[4]=(short)f2b(b.x); r[5]=(short)f2b(b.y); r[6]=(short)f2b(b.z); r[7]=(short)f2b(b.w);
  return r;
}

struct Params {
  const float *x, *noise, *Wq, *Wk, *Wv, *lg, *lb, *gsl, *bsl, *gmlp, *bmlp;
  const float *wih, *whh, *bih, *bhh, *w1, *b1, *w2, *b2, *mu, *lsg;
  float* Upart;    // [3][32][16][512]
  float* Spart;    // [3][32][16][8]
  int*   cnt;      // [3][32]
  float* outp;     // [256][64] f32
};

__global__ void k_zero(int* cnt){
  if (threadIdx.x < 96) cnt[threadIdx.x] = 0;
}

// ---------------------------------------------------------------------------
// Persistent fused kernel, STANDARD launch (graph-capturable).
// 512 blocks x 256 thr, guaranteed >=2 blocks/CU co-resident.
// Block = (b, 256-row n-chunk). k/v parked in registers (validated phase A).
// Per-iteration: in-reg attention -> publish U/S partial -> per-b atomic
// barrier (16 blocks) -> redundant per-block GRU for own b (bit-identical
// across chunks -> no second barrier needed).
// ---------------------------------------------------------------------------
__global__ __launch_bounds__(256, 2) void k_main(Params p)
{
  __shared__ __align__(16) unsigned short uni[4*2560];  // per-wave scratch / gru scratch (aliased)
  __shared__ float U_blk[512];
  __shared__ float S_blk[8];
  __shared__ __align__(16) unsigned short qloc[16*64];
  __shared__ float slotsL[8*64];

  const int tid = threadIdx.x;
  const int w = tid >> 6, ln = tid & 63;
  const int m16 = ln & 15, q = ln >> 4;
  const int blk = blockIdx.x;
  const int b = blk >> 4;
  const int chunk = blk & 15;
  const int nbase = chunk << 8;
  const int cw = w*16 + m16;
  unsigned short* myuni = uni + w*2560;

  // ======== phase A (validated in round 7): LN(x)+project, park k/v in regs ====
  s16x8 gfr[4], bfr[4];
  #pragma unroll
  for (int kb = 0; kb < 4; ++kb){
    gfr[kb] = ld8f(p.lg + kb*32 + q*8);
    bfr[kb] = ld8f(p.lb + kb*32 + q*8);
  }

  s16x8 xA[4][4];   // [t][kb]
  #pragma unroll 2
  for (int t = 0; t < 4; ++t){
    long row = (long)b*4096 + nbase + w*64 + t*16 + m16;
    const float* xr = p.x + row*128;
    float4 xv[8];
    #pragma unroll
    for (int kb = 0; kb < 4; ++kb){
      xv[kb*2]   = *(const float4*)(xr + kb*32 + q*8);
      xv[kb*2+1] = *(const float4*)(xr + kb*32 + q*8 + 4);
    }
    float s1 = 0.f, s2 = 0.f;
    #pragma unroll
    for (int i = 0; i < 8; ++i){
      float4 v = xv[i];
      s1 += v.x + v.y + v.z + v.w;
      s2 += v.x*v.x + v.y*v.y + v.z*v.z + v.w*v.w;
    }
    s1 += __shfl_xor(s1, 16); s2 += __shfl_xor(s2, 16);
    s1 += __shfl_xor(s1, 32); s2 += __shfl_xor(s2, 32);
    float mean = s1 * (1.f/128.f);
    float var  = s2 * (1.f/128.f) - mean*mean;
    float rs = rsqrtf(var + 1e-5f);
    #pragma unroll
    for (int kb = 0; kb < 4; ++kb){
      const float* e0 = (const float*)&xv[kb*2];
      s16x8 fr;
      #pragma unroll
      for (int j = 0; j < 8; ++j){
        float g = b2f((unsigned short)gfr[kb][j]);
        float bb = b2f((unsigned short)bfr[kb][j]);
        fr[j] = (short)f2b((e0[j] - mean)*rs*g + bb);
      }
      xA[t][kb] = fr;
    }
  }

  s16x8 kA[4][2];   // A-frags of k
  {
    s16x8 bwk[4][4];
    #pragma unroll
    for (int nt = 0; nt < 4; ++nt)
      #pragma unroll
      for (int kb = 0; kb < 4; ++kb)
        bwk[kb][nt] = ld8f(p.Wk + (nt*16 + m16)*128 + kb*32 + q*8);
    #pragma unroll
    for (int t = 0; t < 4; ++t){
      f32x4 acc[4] = {{0,0,0,0},{0,0,0,0},{0,0,0,0},{0,0,0,0}};
      #pragma unroll
      for (int kb = 0; kb < 4; ++kb)
        #pragma unroll
        for (int nt = 0; nt < 4; ++nt)
          acc[nt] = mfma16(xA[t][kb], bwk[kb][nt], acc[nt]);
      __syncthreads();
      #pragma unroll
      for (int nt = 0; nt < 4; ++nt)
        #pragma unroll
        for (int rr = 0; rr < 4; ++rr)
          myuni[(q*4+rr)*72 + nt*16 + m16] = f2b(acc[nt][rr]);
      __syncthreads();
      #pragma unroll
      for (int ks = 0; ks < 2; ++ks)
        kA[t][ks] = *(const s16x8*)(myuni + m16*72 + ks*32 + q*8);
    }
  }

  s16x8 vB[4][2];   // B-frags of v
  {
    s16x8 bwv[4][4];
    #pragma unroll
    for (int nt = 0; nt < 4; ++nt)
      #pragma unroll
      for (int kb = 0; kb < 4; ++kb)
        bwv[kb][nt] = ld8f(p.Wv + (nt*16 + m16)*128 + kb*32 + q*8);
    #pragma unroll
    for (int pr = 0; pr < 2; ++pr){
      f32x4 accp[2][4];
      #pragma unroll
      for (int tl = 0; tl < 2; ++tl){
        #pragma unroll
        for (int nt = 0; nt < 4; ++nt){ f32x4 z = {0,0,0,0}; accp[tl][nt] = z; }
        #pragma unroll
        for (int kb = 0; kb < 4; ++kb)
          #pragma unroll
          for (int nt = 0; nt < 4; ++nt)
            accp[tl][nt] = mfma16(xA[pr*2+tl][kb], bwv[kb][nt], accp[tl][nt]);
      }
      __syncthreads();
      #pragma unroll
      for (int tl = 0; tl < 2; ++tl)
        #pragma unroll
        for (int nt = 0; nt < 4; ++nt){
          uint2 pv;
          pv.x = (unsigned int)f2b(accp[tl][nt][0]) | ((unsigned int)f2b(accp[tl][nt][1]) << 16);
          pv.y = (unsigned int)f2b(accp[tl][nt][2]) | ((unsigned int)f2b(accp[tl][nt][3]) << 16);
          *(uint2*)(myuni + (nt*16+m16)*40 + tl*16 + q*4) = pv;
        }
      __syncthreads();
      #pragma unroll
      for (int nt = 0; nt < 4; ++nt)
        vB[nt][pr] = *(const s16x8*)(myuni + (nt*16+m16)*40 + q*8);
    }
  }

  // ======== block-local slot init + q0 (own b) ========
  {
    unsigned short* st = (unsigned short*)((unsigned char*)uni + 4608);
    int r = tid >> 5, c2 = (tid & 31)*2;
    float sl0 = p.mu[r*64+c2]   + (log1pf(expf(p.lsg[r*64+c2]))  +1e-5f)*p.noise[(b*8+r)*64+c2];
    float sl1 = p.mu[r*64+c2+1] + (log1pf(expf(p.lsg[r*64+c2+1]))+1e-5f)*p.noise[(b*8+r)*64+c2+1];
    slotsL[r*64+c2] = sl0; slotsL[r*64+c2+1] = sl1;
    float s1 = sl0+sl1, s2 = sl0*sl0+sl1*sl1;
    #pragma unroll
    for (int m = 1; m < 32; m <<= 1){ s1 += __shfl_xor(s1,m); s2 += __shfl_xor(s2,m); }
    float mean = s1*(1.f/64.f), var = s2*(1.f/64.f)-mean*mean;
    float rs = rsqrtf(var+1e-5f);
    st[r*72+c2]   = f2b((sl0-mean)*rs*p.gsl[c2]  +p.bsl[c2]);
    st[r*72+c2+1] = f2b((sl1-mean)*rs*p.gsl[c2+1]+p.bsl[c2+1]);
    for (int idx = tid; idx < 8*72; idx += 256) st[8*72+idx] = 0;  // pad rows
    __syncthreads();
    f32x4 acc = {0,0,0,0};
    #pragma unroll
    for (int ks = 0; ks < 2; ++ks)
      acc = mfma16(*(const s16x8*)(st + m16*72 + ks*32 + q*8),
                   ld8f(p.Wq + cw*64 + ks*32 + q*8), acc);
    #pragma unroll
    for (int rr = 0; rr < 4; ++rr)
      qloc[(q*4+rr)*64 + cw] = f2b(acc[rr]*0.125f);
    __syncthreads();
  }

  // ======== iterations ========
  for (int it = 0; it < 3; ++it){
    s16x8 bq[2];
    #pragma unroll
    for (int ks = 0; ks < 2; ++ks)
      bq[ks] = *(const s16x8*)(qloc + m16*64 + ks*32 + q*8);

    U_blk[tid] = 0.f; U_blk[tid+256] = 0.f;
    if (tid < 8) S_blk[tid] = 0.f;
    __syncthreads();

    // scores + softmax -> aT (per-wave scratch), validated
    float sacc = 0.f;
    #pragma unroll
    for (int t = 0; t < 4; ++t){
      f32x4 sc = {0,0,0,0};
      sc = mfma16(kA[t][0], bq[0], sc);
      sc = mfma16(kA[t][1], bq[1], sc);
      unsigned short ab[4];
      #pragma unroll
      for (int rr = 0; rr < 4; ++rr){
        float v = (m16 < 8) ? sc[rr] : -3.0e38f;
        float mx = v;
        mx = fmaxf(mx, __shfl_xor(mx, 1));
        mx = fmaxf(mx, __shfl_xor(mx, 2));
        mx = fmaxf(mx, __shfl_xor(mx, 4));
        mx = fmaxf(mx, __shfl_xor(mx, 8));
        float e = (m16 < 8) ? expf(v - mx) : 0.f;
        float sm = e;
        sm += __shfl_xor(sm, 1);
        sm += __shfl_xor(sm, 2);
        sm += __shfl_xor(sm, 4);
        sm += __shfl_xor(sm, 8);
        float a = e/sm + 1e-8f;
        ab[rr] = f2b(a);
        sacc += b2f(ab[rr]);
      }
      if (m16 < 8){
        uint2 pv;
        pv.x = (unsigned int)ab[0] | ((unsigned int)ab[1] << 16);
        pv.y = (unsigned int)ab[2] | ((unsigned int)ab[3] << 16);
        *(uint2*)(myuni + m16*72 + t*16 + q*4) = pv;
      }
    }

    // PV from registers, accumulate block partial in LDS
    #pragma unroll
    for (int nt = 0; nt < 4; ++nt){
      f32x4 au = {0,0,0,0};
      #pragma unroll
      for (int pr = 0; pr < 2; ++pr){
        s16x8 aA = *(const s16x8*)(myuni + m16*72 + pr*32 + q*8);
        au = mfma16(aA, vB[nt][pr], au);
      }
      if (q < 2){
        #pragma unroll
        for (int rr = 0; rr < 4; ++rr)
          atomicAdd(&U_blk[(q*4+rr)*64 + nt*16 + m16], au[rr]);
      }
    }
    sacc += __shfl_xor(sacc, 16);
    sacc += __shfl_xor(sacc, 32);
    if (q == 0 && m16 < 8) atomicAdd(&S_blk[m16], sacc);
    __syncthreads();

    // publish partials (per-(it,b,chunk) slots -> no zeroing, no contention)
    {
      long ub = ((long)(it*32 + b)*16 + chunk)*512;
      p.Upart[ub + tid] = U_blk[tid];
      p.Upart[ub + tid + 256] = U_blk[tid + 256];
      if (tid < 8) p.Spart[(it*32 + b)*128 + chunk*8 + tid] = S_blk[tid];
    }
    __threadfence();
    __syncthreads();
    // per-b barrier: 16 chunk-blocks
    {
      int* c = p.cnt + it*32 + b;
      if (tid == 0){
        __hip_atomic_fetch_add(c, 1, __ATOMIC_ACQ_REL, __HIP_MEMORY_SCOPE_AGENT);
        int guard = 0;
        while (__hip_atomic_load(c, __ATOMIC_ACQUIRE, __HIP_MEMORY_SCOPE_AGENT) < 16){
          __builtin_amdgcn_s_sleep(8);
          if (++guard > (1<<20)) break;   // safety valve: wrong > hung
        }
      }
      __syncthreads();
      __threadfence();
    }

    // reduce the 16 partials (fixed order -> bit-identical across chunks)
    {
      const float* Ub = p.Upart + (long)(it*32 + b)*16*512;
      float a0 = 0.f, a1 = 0.f;
      #pragma unroll
      for (int c2 = 0; c2 < 16; ++c2){
        a0 += Ub[c2*512 + tid];
        a1 += Ub[c2*512 + tid + 256];
      }
      U_blk[tid] = a0; U_blk[tid+256] = a1;
      if (tid < 8){
        const float* Sb = p.Spart + (it*32 + b)*128;
        float s = 0.f;
        #pragma unroll
        for (int c2 = 0; c2 < 16; ++c2) s += Sb[c2*8 + tid];
        S_blk[tid] = s;
      }
    }
    __syncthreads();

    // ---- GRU + LN_mlp + MLP + residual for own b (validated do_gru math,
    //      rows 8..15 padded zero), redundantly per chunk ----
    {
      unsigned char* g = (unsigned char*)uni;
      unsigned short* ut  = (unsigned short*)g;
      unsigned short* ht  = (unsigned short*)(g + 2304);
      unsigned short* st  = (unsigned short*)(g + 4608);
      unsigned short* hid = (unsigned short*)(g + 6912);
      float (*redS)[4] = (float (*)[4])(g + 11264);
      float (*redQ)[4] = (float (*)[4])(g + 11520);

      #pragma unroll
      for (int pr = 0; pr < 4; ++pr){
        int row = pr*4 + w;
        float uu = 0.f, hv = 0.f;
        if (row < 8){
          uu = U_blk[row*64 + ln] / S_blk[row];
          hv = slotsL[row*64 + ln];
        }
        ut[row*72 + ln] = f2b(uu);
        ht[row*72 + ln] = f2b(hv);
      }
      __syncthreads();

      f32x4 axr = {0,0,0,0}, axz = {0,0,0,0}, axn = {0,0,0,0};
      f32x4 ahr = {0,0,0,0}, ahz = {0,0,0,0}, ahn = {0,0,0,0};
      #pragma unroll
      for (int ks = 0; ks < 2; ++ks){
        s16x8 au = *(const s16x8*)(ut + m16*72 + ks*32 + q*8);
        s16x8 ah = *(const s16x8*)(ht + m16*72 + ks*32 + q*8);
        axr = mfma16(au, ld8f(p.wih + (      cw)*64 + ks*32 + q*8), axr);
        axz = mfma16(au, ld8f(p.wih + ( 64 + cw)*64 + ks*32 + q*8), axz);
        axn = mfma16(au, ld8f(p.wih + (128 + cw)*64 + ks*32 + q*8), axn);
        ahr = mfma16(ah, ld8f(p.whh + (      cw)*64 + ks*32 + q*8), ahr);
        ahz = mfma16(ah, ld8f(p.whh + ( 64 + cw)*64 + ks*32 + q*8), ahz);
        ahn = mfma16(ah, ld8f(p.whh + (128 + cw)*64 + ks*32 + q*8), ahn);
      }
      const float bxr = p.bih[cw], bxz = p.bih[64+cw], bxn = p.bih[128+cw];
      const float bhr = p.bhh[cw], bhz = p.bhh[64+cw], bhn = p.bhh[128+cw];
      float sp[4];
      #pragma unroll
      for (int rr = 0; rr < 4; ++rr){
        float xr = axr[rr] + bxr, xz = axz[rr] + bxz, xnv = axn[rr] + bxn;
        float hr = ahr[rr] + bhr, hz = ahz[rr] + bhz, hn = ahn[rr] + bhn;
        float rg = 1.f / (1.f + expf(-(xr + hr)));
        float zg = 1.f / (1.f + expf(-(xz + hz)));
        float ng = tanhf(xnv + rg*hn);
        float hv = b2f(ht[(q*4 + rr)*72 + cw]);
        sp[rr] = (1.f - zg)*ng + zg*hv;
      }

      float s1v[4], s2v[4];
      #pragma unroll
      for (int rr = 0; rr < 4; ++rr){ s1v[rr] = sp[rr]; s2v[rr] = sp[rr]*sp[rr]; }
      #pragma unroll
      for (int m = 1; m < 16; m <<= 1){
        #pragma unroll
        for (int rr = 0; rr < 4; ++rr){
          s1v[rr] += __shfl_xor(s1v[rr], m);
          s2v[rr] += __shfl_xor(s2v[rr], m);
        }
      }
      if (m16 == 0){
        #pragma unroll
        for (int rr = 0; rr < 4; ++rr){ redS[q*4+rr][w] = s1v[rr]; redQ[q*4+rr][w] = s2v[rr]; }
      }
      __syncthreads();
      float sl_[4];
      {
        const float gm = p.gmlp[cw], bm = p.bmlp[cw];
        #pragma unroll
        for (int rr = 0; rr < 4; ++rr){
          f32x4 aS = *(const f32x4*)redS[q*4+rr];
          f32x4 aQ = *(const f32x4*)redQ[q*4+rr];
          float tS = aS[0]+aS[1]+aS[2]+aS[3];
          float tQ = aQ[0]+aQ[1]+aQ[2]+aQ[3];
          float mean = tS*(1.f/64.f);
          float var  = tQ*(1.f/64.f) - mean*mean;
          float rs = rsqrtf(var + 1e-5f);
          sl_[rr] = (sp[rr] - mean)*rs*gm + bm;
          st[(q*4+rr)*72 + cw] = f2b(sl_[rr]);
        }
      }
      __syncthreads();

      #pragma unroll
      for (int t2 = 0; t2 < 2; ++t2){
        int col = (w*2 + t2)*16 + m16;
        f32x4 acc = {0,0,0,0};
        #pragma unroll
        for (int ks = 0; ks < 2; ++ks){
          s16x8 a = *(const s16x8*)(st + m16*72 + ks*32 + q*8);
          acc = mfma16(a, ld8f(p.w1 + col*64 + ks*32 + q*8), acc);
        }
        float bb = p.b1[col];
        #pragma unroll
        for (int rr = 0; rr < 4; ++rr)
          hid[(q*4+rr)*136 + col] = f2b(fmaxf(acc[rr] + bb, 0.f));
      }
      __syncthreads();

      float snew[4];
      {
        f32x4 acc = {0,0,0,0};
        #pragma unroll
        for (int ks = 0; ks < 4; ++ks){
          s16x8 a = *(const s16x8*)(hid + m16*136 + ks*32 + q*8);
          acc = mfma16(a, ld8f(p.w2 + cw*128 + ks*32 + q*8), acc);
        }
        float bb = p.b2[cw];
        #pragma unroll
        for (int rr = 0; rr < 4; ++rr){
          snew[rr] = sl_[rr] + acc[rr] + bb;
          int row = q*4 + rr;
          if (row < 8){
            slotsL[row*64 + cw] = snew[rr];
            if (it == 2 && chunk == 0)
              p.outp[(b*8 + row)*64 + cw] = snew[rr];
          }
        }
      }

      if (it < 2){
        #pragma unroll
        for (int rr = 0; rr < 4; ++rr){ s1v[rr] = snew[rr]; s2v[rr] = snew[rr]*snew[rr]; }
        #pragma unroll
        for (int m = 1; m < 16; m <<= 1){
          #pragma unroll
          for (int rr = 0; rr < 4; ++rr){
            s1v[rr] += __shfl_xor(s1v[rr], m);
            s2v[rr] += __shfl_xor(s2v[rr], m);
          }
        }
        __syncthreads();
        if (m16 == 0){
          #pragma unroll
          for (int rr = 0; rr < 4; ++rr){ redS[q*4+rr][w] = s1v[rr]; redQ[q*4+rr][w] = s2v[rr]; }
        }
        __syncthreads();
        {
          const float gs = p.gsl[cw], bs = p.bsl[cw];
          #pragma unroll
          for (int rr = 0; rr < 4; ++rr){
            f32x4 aS = *(const f32x4*)redS[q*4+rr];
            f32x4 aQ = *(const f32x4*)redQ[q*4+rr];
            float tS = aS[0]+aS[1]+aS[2]+aS[3];
            float tQ = aQ[0]+aQ[1]+aQ[2]+aQ[3];
            float mean = tS*(1.f/64.f);
            float var  = tQ*(1.f/64.f) - mean*mean;
            float rs = rsqrtf(var + 1e-5f);
            st[(q*4+rr)*72 + cw] = f2b((snew[rr] - mean)*rs*gs + bs);
          }
        }
        __syncthreads();
        {
          f32x4 acc = {0,0,0,0};
          #pragma unroll
          for (int ks = 0; ks < 2; ++ks){
            s16x8 a = *(const s16x8*)(st + m16*72 + ks*32 + q*8);
            acc = mfma16(a, ld8f(p.Wq + cw*64 + ks*32 + q*8), acc);
          }
          #pragma unroll
          for (int rr = 0; rr < 4; ++rr)
            qloc[(q*4+rr)*64 + cw] = f2b(acc[rr] * 0.125f);
        }
      }
      __syncthreads();
    }
  }
}

// ---------------------------------------------------------------------------
extern "C" void kernel_launch(void* const* d_in, const int* in_sizes, int n_in,
                              void* d_out, int out_size, void* d_ws, size_t ws_size,
                              hipStream_t stream)
{
  Params prm;
  prm.x    = (const float*)d_in[0];
  prm.noise= (const float*)d_in[1];
  prm.Wq   = (const float*)d_in[2];
  prm.Wk   = (const float*)d_in[3];
  prm.Wv   = (const float*)d_in[4];
  prm.lg   = (const float*)d_in[5];
  prm.lb   = (const float*)d_in[6];
  prm.gsl  = (const float*)d_in[7];
  prm.bsl  = (const float*)d_in[8];
  prm.gmlp = (const float*)d_in[9];
  prm.bmlp = (const float*)d_in[10];
  prm.wih  = (const float*)d_in[11];
  prm.whh  = (const float*)d_in[12];
  prm.bih  = (const float*)d_in[13];
  prm.bhh  = (const float*)d_in[14];
  prm.w1   = (const float*)d_in[15];
  prm.b1   = (const float*)d_in[16];
  prm.w2   = (const float*)d_in[17];
  prm.b2   = (const float*)d_in[18];
  prm.mu   = (const float*)d_in[19];
  prm.lsg  = (const float*)d_in[20];

  char* ws = (char*)d_ws;
  prm.cnt   = (int*)(ws);               // 96 ints (zeroed by k_zero each launch)
  prm.Spart = (float*)(ws + 1024);      // 3*32*16*8 f32 = 48 KB
  prm.Upart = (float*)(ws + 65536);     // 3*32*16*512 f32 = 3 MB
  prm.outp  = (float*)d_out;

  hipLaunchKernelGGL(k_zero, dim3(1), dim3(128), 0, stream, prm.cnt);
  hipLaunchKernelGGL(k_main, dim3(512), dim3(256), 0, stream, prm);
  (void)in_sizes; (void)n_in; (void)out_size; (void)ws_size;
}